// Round 12
// baseline (318.210 us; speedup 1.0000x reference)
//
#include <hip/hip_runtime.h>
#include <hip/hip_bf16.h>

// CARAFE fp32 pipeline. x(4,256,64,64), Wc(64,256), bc(64), We(100,64,3,3),
// be(100) -> out(4,256,128,128). SF=2 K=5 G=1 CC=64 EK=3. All I/O fp32.
//
// ws layout (fp32 elements):
//   comp  [4][64][66*66]   zero-padded halo   @ 0          (1,115,136)
//   Wr2   [ij4][kt5][cc64][48]  q*5+kk packed @ 1,115,136  (61,440 of 64,512)
//   logit [16384 px][100]  e = 4k+ij          @ 1,179,648  (1,638,400)
//     NB: first 16,384 floats of logit double as WcT[c256][cc64] during
//     k0->k1; the hipMemsetAsync between k1 and k2 clobbers/zeroes it.
// total 11,272,192 B (unchanged). Host-gated on ws_size; fallback = fused.
//
// Round 15 (this round): k2 v8 -- concurrency, not pipes. Evidence: v3/v6/v7
// invariant at ~49us across conflict counts (6.15M->0.26M) and restrict
// split; VALU 44%, DS ~20-50%, SMEM tiny -> NOTHING saturated. k2 is
// latency-bound at 5 blocks/CU avg (20/32 wave slots); per-wave ILP is
// limited because s_load (weights) and ds_read (cv) share lgkmcnt and SMEM
// returns out-of-order -> conservative drains serialize each channel.
// v8: channel-split cb in {0,1}: 32 channels/block, LDS 15.4KB, grid 2560
// -> 8 blocks/CU = 32 waves/CU (HW max). Partial sums combined via
// global atomicAdd onto a zeroed logit page (hipMemsetAsync after k1);
// be bias folded into k2s's read. Total FMA/DS/staging bytes unchanged.

#define COMP_F 0
#define WR_F   1115136
#define LOG_F  1179648
#define WS_NEED 11272192ull
#define CSTR 4356  // 66*66 comp per-channel stride

// ---------------- K0: Wr2 repack + WcT transpose ------------------------
// job1 (tid < 57600): We(100,576) -> Wr2[ij][kt][cc][48], row = q*5+kk.
// job2 (tid >= 57600): Wc(64,256) -> WcT[c][cc] @ LOG_F (16,384 floats).
__global__ void k0_wr(const float* __restrict__ We, const float* __restrict__ Wc,
                      float* __restrict__ ws) {
    int tid = blockIdx.x * blockDim.x + threadIdx.x;
    if (tid < 57600) {
        int kk = tid % 5;
        int q  = (tid / 5) % 9;
        int cc = (tid / 45) % 64;
        int kt = (tid / 2880) % 5;
        int ij = tid / 14400;
        ws[WR_F + (size_t)(((ij * 5 + kt) * 64 + cc)) * 48 + q * 5 + kk] =
            We[(size_t)(4 * (kt * 5 + kk) + ij) * 576 + cc * 9 + q];
    } else if (tid < 57600 + 16384) {
        int t2 = tid - 57600;
        int c = t2 >> 6, cc = t2 & 63;
        ws[LOG_F + t2] = Wc[cc * 256 + c];
    }
}

// ---------------- K1 v4: 1x1 compressor 256->64, padded comp out --------
// grid 512 = ccq*64 + pxtile; block 256thr; thread = one pixel, 8 cc.
// Weights from WcT via s_load_dwordx8 (restrict args). Coalesced x loads.
__global__ __launch_bounds__(256) void k1_comp(const float* __restrict__ x,
                                               const float* __restrict__ bc,
                                               const float* __restrict__ wT,
                                               float* __restrict__ comp) {
    int b      = blockIdx.x;
    int pxtile = b & 63;       // 0..63 ; b%8 = pxtile%8 -> cc-siblings same XCD
    int ccq    = b >> 6;       // 0..7, wave-uniform
    int tid = threadIdx.x;
    int n   = pxtile >> 4;
    int off = (pxtile & 15) * 256 + tid;   // 0..4095 within image
    int h = off >> 6, w = off & 63;
    int cc0 = ccq * 8;

    const float* xp = x + (size_t)n * 256 * 4096 + off;

    float acc[8];
#pragma unroll
    for (int u = 0; u < 8; ++u) acc[u] = 0.f;

#pragma unroll 8
    for (int c = 0; c < 256; ++c) {
        float xv = xp[(size_t)c * 4096];
        const float* wr = wT + c * 64 + cc0;   // uniform -> s_load_dwordx8
#pragma unroll
        for (int u = 0; u < 8; ++u) acc[u] += xv * wr[u];
    }

    float* compb = comp + (size_t)(n * 64 + cc0) * CSTR;
#pragma unroll
    for (int u = 0; u < 8; ++u) {
        float* cb_ = compb + (size_t)u * CSTR;
        cb_[(h + 1) * 66 + (w + 1)] = acc[u] + bc[cc0 + u];
        // zero halo border (pad=1 of the 3x3 conv)
        if (w < 2) cb_[(h + 1) * 66 + (w ? 65 : 0)] = 0.f;
        if (h == 0)  { cb_[w] = 0.f;           if (w < 2) cb_[64 + w] = 0.f; }
        if (h == 63) { cb_[65 * 66 + w] = 0.f; if (w < 2) cb_[65 * 66 + 64 + w] = 0.f; }
    }
}

// ---------------- K2 v8: 3x3 encoder -> partial logit sums --------------
// grid 2560 = sub*256 + tile; sub = kt*2 + cb. Block: 32 channels
// (cb*32..+31), 8x8 px tile, 4 ij-waves. LDS 15.4KB -> 8 blocks/CU =
// 32 waves/CU (HW max). Conflict-free lane map (r13). SGPR weights.
// Output: atomicAdd partials onto the memset-zeroed logit region.
__global__ __launch_bounds__(256) void k2_enc(const float* __restrict__ comp,
                                              const float* __restrict__ wr,
                                              float* __restrict__ logits) {
    __shared__ __align__(16) float compT[32 * 120];  // 15360 B
    int b    = blockIdx.x;
    int tile = b & 255;                              // low bits: same-tile
    int sub  = b >> 8;                               // 0..9
    int kt   = sub >> 1;                             // 0..4
    int cb   = sub & 1;                              // 0..1 channel half
    int n = tile >> 6, th = (tile >> 3) & 7, tw = tile & 7;
    int h0 = th * 8, w0 = tw * 8;
    int tid = threadIdx.x;

    const float* compn = comp + (size_t)(n * 64 + cb * 32) * CSTR;
    // stage 32-channel comp halo tile: compT[c*120 + r*12 + q]
    for (int e = tid; e < 3200; e += 256) {
        int c = e / 100, rq = e % 100, r = rq / 10, q = rq % 10;
        compT[c * 120 + r * 12 + q] =
            compn[(size_t)c * CSTR + (h0 + r) * 66 + (w0 + q)];
    }
    __syncthreads();

    int lane = tid & 63;
    int ij   = __builtin_amdgcn_readfirstlane(tid >> 6);  // force scalar
    int py = lane & 7, pxx = lane >> 3;   // conflict-free bank walk (r13)

    const float* wb = wr + (size_t)((ij * 5 + kt) * 64 + cb * 32) * 48;

    float acc[5];
#pragma unroll
    for (int kk = 0; kk < 5; ++kk) acc[kk] = 0.f;

#pragma unroll 2
    for (int c = 0; c < 32; ++c) {
        const float* cp = compT + c * 120 + py * 12 + pxx;
        float cv[9];
#pragma unroll
        for (int dy = 0; dy < 3; ++dy)
#pragma unroll
            for (int dx = 0; dx < 3; ++dx)
                cv[dy * 3 + dx] = cp[dy * 12 + dx];
        const float* w = wb + c * 48;                // uniform -> s_load
#pragma unroll
        for (int q = 0; q < 9; ++q) {
            float v = cv[q];
#pragma unroll
            for (int kk = 0; kk < 5; ++kk)
                acc[kk] += v * w[q * 5 + kk];        // v_fmac v, s, v
        }
    }

    float* lp = logits +
                (size_t)(n * 4096 + (h0 + py) * 64 + (w0 + pxx)) * 100 + ij;
#pragma unroll
    for (int kk = 0; kk < 5; ++kk)
        atomicAdd(lp + 4 * (kt * 5 + kk), acc[kk]);
}

// ---------------- K2s v3: in-place softmax (+be bias), LDS-coalesced ----
// grid 256 x 256thr: block handles 64 px. Coalesced float4 I/O through
// LDS. Bias be[4k+ij] added at read (logits hold raw partial sums).
__global__ __launch_bounds__(256) void k2s_sm(const float* __restrict__ be,
                                              float* __restrict__ logits) {
    __shared__ __align__(16) float L[64 * 100];  // 25600 B
    float* gp = logits + (size_t)blockIdx.x * 6400;
    int tid = threadIdx.x;

    for (int e4 = tid; e4 < 1600; e4 += 256)
        ((float4*)L)[e4] = ((const float4*)gp)[e4];
    __syncthreads();

    int pxl = tid >> 2, ij = tid & 3;
    float* p = L + pxl * 100 + ij;
    float m[25];
#pragma unroll
    for (int k = 0; k < 25; ++k) m[k] = p[4 * k] + be[4 * k + ij];
    float mx = m[0];
#pragma unroll
    for (int k = 1; k < 25; ++k) mx = fmaxf(mx, m[k]);
    float ss = 0.f;
#pragma unroll
    for (int k = 0; k < 25; ++k) { m[k] = __expf(m[k] - mx); ss += m[k]; }
    float inv = 1.f / ss;
#pragma unroll
    for (int k = 0; k < 25; ++k) p[4 * k] = m[k] * inv;
    __syncthreads();

    for (int e4 = tid; e4 < 1600; e4 += 256)
        ((float4*)gp)[e4] = ((const float4*)L)[e4];
}

// ---------------- K3 v4: reassembly (masks pre-normalized) --------------
// grid 1024 x 256thr: b = cchunk*64 + tile. 16x16 px tile, 16-c chunk.
// x tile in LDS as [cg8][r20][q20][2]; one ds_read_b64 per tap serves 2
// channels. Taps OUTER, channels inner; resident float2 A[8][4] (64 VGPR,
// statically indexed). Plain launch_bounds(256) (min-waves hint spills).
__global__ __launch_bounds__(256) void k3_out(const float* __restrict__ x,
                                              const float* __restrict__ logits,
                                              float* __restrict__ out) {
    __shared__ __align__(16) float xt[8 * 20 * 42];  // 26880 B
    int b      = blockIdx.x;
    int tile   = b & 63;
    int cchunk = b >> 6;
    int n = tile >> 4, ty0 = ((tile >> 2) & 3) * 16, tx0 = (tile & 3) * 16;
    int c0 = cchunk * 16;

    int py = threadIdx.x >> 4, pxx = threadIdx.x & 15;
    int h = ty0 + py, w = tx0 + pxx;

    // stage x halo tile as float2 (halo col origin tx0-2 is even -> the
    // 20-wide row is 10 aligned float2s, all-or-nothing in bounds).
    const float* xn = x + (size_t)(n * 256 + c0) * 4096;
    for (int e2 = threadIdx.x; e2 < 3200; e2 += 256) {
        int c = e2 / 200, rem = e2 % 200, r = rem / 10, q2 = rem % 10;
        int hh = ty0 + r - 2, ww = tx0 + 2 * q2 - 2;
        float2 v = {0.f, 0.f};
        if (hh >= 0 && hh < 64 && ww >= 0 && ww < 64)
            v = *(const float2*)(xn + (size_t)c * 4096 + hh * 64 + ww);
        int a0 = (c >> 1) * 840 + r * 42 + 4 * q2 + (c & 1);
        xt[a0]     = v.x;
        xt[a0 + 2] = v.y;
    }
    __syncthreads();

    const float* lp = logits + (size_t)(n * 4096 + h * 64 + w) * 100;
    const float* vb = xt + py * 42 + pxx * 2;

    float2 A[8][4];
#pragma unroll
    for (int cg = 0; cg < 8; ++cg)
#pragma unroll
        for (int u = 0; u < 4; ++u) A[cg][u] = {0.f, 0.f};

    for (int dy = 0; dy < 5; ++dy) {
        const float4* mkp = (const float4*)lp + dy * 5;  // 5 taps this row
        const float* vrow = vb + dy * 42;
#pragma unroll
        for (int dx = 0; dx < 5; ++dx) {
            float4 mk = mkp[dx];                         // transient, L2-hot
#pragma unroll
            for (int cg = 0; cg < 8; ++cg) {
                float2 v = *(const float2*)(vrow + cg * 840 + dx * 2);
                A[cg][0].x += v.x * mk.x; A[cg][0].y += v.y * mk.x;
                A[cg][1].x += v.x * mk.y; A[cg][1].y += v.y * mk.y;
                A[cg][2].x += v.x * mk.z; A[cg][2].y += v.y * mk.z;
                A[cg][3].x += v.x * mk.w; A[cg][3].y += v.y * mk.w;
            }
        }
    }

#pragma unroll
    for (int cg = 0; cg < 8; ++cg) {
        int c = cg * 2;
        size_t ob0 = (((size_t)(n * 256 + c0 + c) * 128) + 2 * h) * 128 + 2 * w;
        float2 r0 = {A[cg][0].x, A[cg][1].x}, r1 = {A[cg][2].x, A[cg][3].x};
        *(float2*)(out + ob0)       = r0;
        *(float2*)(out + ob0 + 128) = r1;
        size_t ob1 = ob0 + 16384;
        float2 r2 = {A[cg][0].y, A[cg][1].y}, r3 = {A[cg][2].y, A[cg][3].y};
        *(float2*)(out + ob1)       = r2;
        *(float2*)(out + ob1 + 128) = r3;
    }
}

// ---------------- Fallback: fused kernel, fp32-only ---------------------
__global__ __launch_bounds__(256) void k_fused(const float* __restrict__ x,
                                               const float* __restrict__ Wc,
                                               const float* __restrict__ bc,
                                               const float* __restrict__ We,
                                               const float* __restrict__ be,
                                               float* __restrict__ out) {
    __shared__ float compS[64 * 101];
    int n = blockIdx.x >> 6, tile = blockIdx.x & 63;
    int ty0 = (tile >> 3) * 8, tx0 = (tile & 7) * 8;
    const float* xn = x + (size_t)n * 256 * 4096;
    {
        int pa = threadIdx.x & 127;
        int ga = __builtin_amdgcn_readfirstlane(threadIdx.x >> 7);
        bool act = pa < 100;
        int ah = ty0 + pa / 10 - 1, aw = tx0 + pa % 10 - 1;
        bool inb = act && ah >= 0 && ah < 64 && aw >= 0 && aw < 64;
        int xoff = ah * 64 + aw;
        float acc[32];
#pragma unroll
        for (int i = 0; i < 32; ++i) acc[i] = 0.f;
        for (int c = 0; c < 256; ++c) {
            float xv = inb ? xn[(size_t)c * 4096 + xoff] : 0.f;
#pragma unroll
            for (int i = 0; i < 32; ++i) acc[i] += xv * Wc[(ga * 32 + i) * 256 + c];
        }
        if (act)
#pragma unroll
            for (int i = 0; i < 32; ++i) {
                int cc = ga * 32 + i;
                compS[cc * 101 + pa] = inb ? acc[i] + bc[cc] : 0.f;
            }
    }
    __syncthreads();
    int px = threadIdx.x & 63;
    int ij = __builtin_amdgcn_readfirstlane(threadIdx.x >> 6);
    int py = px >> 3, pxx = px & 7;
    int h = ty0 + py, w = tx0 + pxx;
    float m[25];
#pragma unroll
    for (int k = 0; k < 25; ++k) m[k] = be[4 * k + ij];
    for (int cc = 0; cc < 64; ++cc) {
        float cv[9];
#pragma unroll
        for (int dy = 0; dy < 3; ++dy)
#pragma unroll
            for (int dx = 0; dx < 3; ++dx)
                cv[dy * 3 + dx] = compS[cc * 101 + (py + dy) * 10 + (pxx + dx)];
        int base = cc * 9;
#pragma unroll
        for (int k = 0; k < 25; ++k) {
            int eb = (4 * k + ij) * 576 + base;
            float s = 0.f;
#pragma unroll
            for (int qb = 0; qb < 9; ++qb) s += cv[qb] * We[eb + qb];
            m[k] += s;
        }
    }
    float mxv = m[0];
#pragma unroll
    for (int k = 1; k < 25; ++k) mxv = fmaxf(mxv, m[k]);
    float ss = 0.f;
#pragma unroll
    for (int k = 0; k < 25; ++k) { m[k] = __expf(m[k] - mxv); ss += m[k]; }
    float inv = 1.f / ss;
#pragma unroll
    for (int k = 0; k < 25; ++k) m[k] *= inv;
    int offs[25];
    unsigned vm = 0;
#pragma unroll
    for (int t = 0; t < 25; ++t) {
        int hh = h + t / 5 - 2, ww = w + t % 5 - 2;
        bool v = hh >= 0 && hh < 64 && ww >= 0 && ww < 64;
        offs[t] = v ? hh * 64 + ww : 0;
        if (v) vm |= 1u << t;
    }
    size_t outp = ((size_t)n * 256 * 128 + (2 * h + (ij >> 1))) * 128 + (2 * w + (ij & 1));
    for (int c = 0; c < 256; ++c) {
        const float* xc = xn + (size_t)c * 4096;
        float sum = 0.f;
#pragma unroll
        for (int t = 0; t < 25; ++t) {
            float v = ((vm >> t) & 1u) ? xc[offs[t]] : 0.f;
            sum += v * m[t];
        }
        out[outp + (size_t)c * 16384] = sum;
    }
}

extern "C" void kernel_launch(void* const* d_in, const int* in_sizes, int n_in,
                              void* d_out, int out_size, void* d_ws, size_t ws_size,
                              hipStream_t stream) {
    const float* x  = (const float*)d_in[0];
    const float* Wc = (const float*)d_in[1];
    const float* bc = (const float*)d_in[2];
    const float* We = (const float*)d_in[3];
    const float* be = (const float*)d_in[4];
    float* out = (float*)d_out;

    if (ws_size >= WS_NEED && d_ws != nullptr) {
        float* ws = (float*)d_ws;
        float* comp   = ws + COMP_F;
        float* wr     = ws + WR_F;
        float* logits = ws + LOG_F;
        hipLaunchKernelGGL(k0_wr,   dim3(289),  dim3(256), 0, stream, We, Wc, ws);
        hipLaunchKernelGGL(k1_comp, dim3(512),  dim3(256), 0, stream,
                           x, bc, /*wT=*/logits, comp);
        // zero the logit accumulation page (also retires the WcT overlap)
        hipMemsetAsync(logits, 0, 1638400 * sizeof(float), stream);
        hipLaunchKernelGGL(k2_enc,  dim3(2560), dim3(256), 0, stream,
                           comp, wr, logits);
        hipLaunchKernelGGL(k2s_sm,  dim3(256),  dim3(256), 0, stream,
                           be, logits);
        hipLaunchKernelGGL(k3_out,  dim3(1024), dim3(256), 0, stream,
                           x, logits, out);
    } else {
        hipLaunchKernelGGL(k_fused, dim3(256),  dim3(256), 0, stream,
                           x, Wc, bc, We, be, out);
    }
}

// Round 13
// 181.969 us; speedup vs baseline: 1.7487x; 1.7487x over previous
//
#include <hip/hip_runtime.h>
#include <hip/hip_bf16.h>

// CARAFE fp32 pipeline. x(4,256,64,64), Wc(64,256), bc(64), We(100,64,3,3),
// be(100) -> out(4,256,128,128). SF=2 K=5 G=1 CC=64 EK=3. All I/O fp32.
//
// ws layout (fp32 elements):
//   comp  [4][64][66*66]   zero-padded halo   @ 0          (1,115,136)
//   Wr2   [ij4][kt5][cc64][48]  q*5+kk packed @ 1,115,136  (61,440 of 64,512)
//   logit [16384 px][100]  e = 4k+ij          @ 1,179,648  (1,638,400)
//     NB: first 16,384 floats of logit double as WcT[c256][cc64] during
//     k0->k1 (dead until k2 overwrites logits; stream-serialized).
// total 11,272,192 B. Host-gated on ws_size; fallback = fused kernel.
//
// Round 16 (this round): REVERT r12's atomics (WRITE 102MB, VALU 12%,
// 189us -- atomic RMW stream serialized). Keep the concurrency diagnosis
// (v3/v6/v7 invariant ~49us, nothing saturated, 20/32 wave slots) but get
// occupancy with SINGLE-WRITER stores: k2 v9 = 512-thr blocks (8 waves),
// wave = cb*4+ij; each wave does 32 channels with the v7 inner loop;
// cb=1 waves deposit acc[5] in a 5.1KB LDS redbuf (stride 5, coprime 32,
// conflict-free); barrier; cb=0 waves add + store. LDS 35.8KB, 4 blocks/CU
// = 32 waves/CU (HW max), no atomics/memset/extra ws. be back in k2 init.

#define COMP_F 0
#define WR_F   1115136
#define LOG_F  1179648
#define WS_NEED 11272192ull
#define CSTR 4356  // 66*66 comp per-channel stride

// ---------------- K0: Wr2 repack + WcT transpose ------------------------
// job1 (tid < 57600): We(100,576) -> Wr2[ij][kt][cc][48], row = q*5+kk.
// job2 (tid >= 57600): Wc(64,256) -> WcT[c][cc] @ LOG_F (16,384 floats).
__global__ void k0_wr(const float* __restrict__ We, const float* __restrict__ Wc,
                      float* __restrict__ ws) {
    int tid = blockIdx.x * blockDim.x + threadIdx.x;
    if (tid < 57600) {
        int kk = tid % 5;
        int q  = (tid / 5) % 9;
        int cc = (tid / 45) % 64;
        int kt = (tid / 2880) % 5;
        int ij = tid / 14400;
        ws[WR_F + (size_t)(((ij * 5 + kt) * 64 + cc)) * 48 + q * 5 + kk] =
            We[(size_t)(4 * (kt * 5 + kk) + ij) * 576 + cc * 9 + q];
    } else if (tid < 57600 + 16384) {
        int t2 = tid - 57600;
        int c = t2 >> 6, cc = t2 & 63;
        ws[LOG_F + t2] = Wc[cc * 256 + c];
    }
}

// ---------------- K1 v4: 1x1 compressor 256->64, padded comp out --------
// grid 512 = ccq*64 + pxtile; block 256thr; thread = one pixel, 8 cc.
// Weights from WcT via s_load_dwordx8 (restrict args). Coalesced x loads.
__global__ __launch_bounds__(256) void k1_comp(const float* __restrict__ x,
                                               const float* __restrict__ bc,
                                               const float* __restrict__ wT,
                                               float* __restrict__ comp) {
    int b      = blockIdx.x;
    int pxtile = b & 63;       // 0..63 ; b%8 = pxtile%8 -> cc-siblings same XCD
    int ccq    = b >> 6;       // 0..7, wave-uniform
    int tid = threadIdx.x;
    int n   = pxtile >> 4;
    int off = (pxtile & 15) * 256 + tid;   // 0..4095 within image
    int h = off >> 6, w = off & 63;
    int cc0 = ccq * 8;

    const float* xp = x + (size_t)n * 256 * 4096 + off;

    float acc[8];
#pragma unroll
    for (int u = 0; u < 8; ++u) acc[u] = 0.f;

#pragma unroll 8
    for (int c = 0; c < 256; ++c) {
        float xv = xp[(size_t)c * 4096];
        const float* wr = wT + c * 64 + cc0;   // uniform -> s_load_dwordx8
#pragma unroll
        for (int u = 0; u < 8; ++u) acc[u] += xv * wr[u];
    }

    float* compb = comp + (size_t)(n * 64 + cc0) * CSTR;
#pragma unroll
    for (int u = 0; u < 8; ++u) {
        float* cb_ = compb + (size_t)u * CSTR;
        cb_[(h + 1) * 66 + (w + 1)] = acc[u] + bc[cc0 + u];
        // zero halo border (pad=1 of the 3x3 conv)
        if (w < 2) cb_[(h + 1) * 66 + (w ? 65 : 0)] = 0.f;
        if (h == 0)  { cb_[w] = 0.f;           if (w < 2) cb_[64 + w] = 0.f; }
        if (h == 63) { cb_[65 * 66 + w] = 0.f; if (w < 2) cb_[65 * 66 + 64 + w] = 0.f; }
    }
}

// ---------------- K2 v9: 3x3 encoder, 8-wave blocks + LDS reduce --------
// grid 1280 = kt*256 + tile; block 512 thr = 8 waves; wave = cb*4 + ij.
// Each wave: 32 channels (cb half) x 8x8 px, v7 inner loop (conflict-free
// lane map, SGPR weights). cb=1 waves deposit acc[5] into redS (stride 5,
// coprime with 32 banks = conflict-free); barrier; cb=0 waves add + store
// (single writer -- no atomics). LDS 30720+5120 = 35840B -> 4 blocks/CU =
// 32 waves/CU (HW max; v7 was 20).
__global__ __launch_bounds__(512) void k2_enc(const float* __restrict__ be,
                                              const float* __restrict__ comp,
                                              const float* __restrict__ wr,
                                              float* __restrict__ logits) {
    __shared__ __align__(16) float compT[64 * 120];  // 30720 B
    __shared__ __align__(16) float redS[4 * 64 * 5]; //  5120 B
    int b    = blockIdx.x;
    int tile = b & 255;                              // low bits: same-tile
    int kt   = b >> 8;                               // 0..4, siblings same XCD
    int n = tile >> 6, th = (tile >> 3) & 7, tw = tile & 7;
    int h0 = th * 8, w0 = tw * 8;
    int tid = threadIdx.x;

    const float* compn = comp + (size_t)n * 64 * CSTR;
    // stage comp halo tile: compT[c*120 + r*12 + q] = comp[c][h0+r][w0+q]
    for (int e = tid; e < 6400; e += 512) {
        int c = e / 100, rq = e % 100, r = rq / 10, q = rq % 10;
        compT[c * 120 + r * 12 + q] =
            compn[(size_t)c * CSTR + (h0 + r) * 66 + (w0 + q)];
    }
    __syncthreads();

    int lane = tid & 63;
    int wid  = __builtin_amdgcn_readfirstlane(tid >> 6);  // 0..7, scalar
    int ij   = wid & 3;
    int cb   = wid >> 2;                   // channel half: 0 or 1
    int py = lane & 7, pxx = lane >> 3;    // conflict-free bank walk (r13)

    const float* wb = wr + (size_t)((ij * 5 + kt) * 64 + cb * 32) * 48;
    const float* ct = compT + cb * 32 * 120;

    float acc[5];
#pragma unroll
    for (int kk = 0; kk < 5; ++kk)
        acc[kk] = cb ? 0.f : be[4 * (kt * 5 + kk) + ij];

#pragma unroll 2
    for (int c = 0; c < 32; ++c) {
        const float* cp = ct + c * 120 + py * 12 + pxx;
        float cv[9];
#pragma unroll
        for (int dy = 0; dy < 3; ++dy)
#pragma unroll
            for (int dx = 0; dx < 3; ++dx)
                cv[dy * 3 + dx] = cp[dy * 12 + dx];
        const float* w = wb + c * 48;                // uniform -> s_load
#pragma unroll
        for (int q = 0; q < 9; ++q) {
            float v = cv[q];
#pragma unroll
            for (int kk = 0; kk < 5; ++kk)
                acc[kk] += v * w[q * 5 + kk];        // v_fmac v, s, v
        }
    }

    // cross-wave reduce: cb=1 deposits, cb=0 adds and stores (disjoint px).
    if (cb) {
        float* rp = redS + (ij * 64 + lane) * 5;
#pragma unroll
        for (int kk = 0; kk < 5; ++kk) rp[kk] = acc[kk];
    }
    __syncthreads();
    if (!cb) {
        const float* rp = redS + (ij * 64 + lane) * 5;
        float* lp = logits +
                    (size_t)(n * 4096 + (h0 + py) * 64 + (w0 + pxx)) * 100 + ij;
#pragma unroll
        for (int kk = 0; kk < 5; ++kk)
            lp[4 * (kt * 5 + kk)] = acc[kk] + rp[kk];
    }
}

// ---------------- K2s v2: in-place softmax, LDS-coalesced ---------------
// grid 256 x 256thr: block handles 64 px. Coalesced float4 I/O through
// LDS. Softmax thread-task = (pxl, ij); LDS reads at pxl*100+4k+ij are
// 2-way bank aliased max (100 mod 32 = 4) = free.
__global__ __launch_bounds__(256) void k2s_sm(float* __restrict__ logits) {
    __shared__ __align__(16) float L[64 * 100];  // 25600 B
    float* gp = logits + (size_t)blockIdx.x * 6400;
    int tid = threadIdx.x;

    for (int e4 = tid; e4 < 1600; e4 += 256)
        ((float4*)L)[e4] = ((const float4*)gp)[e4];
    __syncthreads();

    int pxl = tid >> 2, ij = tid & 3;
    float* p = L + pxl * 100 + ij;
    float m[25];
#pragma unroll
    for (int k = 0; k < 25; ++k) m[k] = p[4 * k];
    float mx = m[0];
#pragma unroll
    for (int k = 1; k < 25; ++k) mx = fmaxf(mx, m[k]);
    float ss = 0.f;
#pragma unroll
    for (int k = 0; k < 25; ++k) { m[k] = __expf(m[k] - mx); ss += m[k]; }
    float inv = 1.f / ss;
#pragma unroll
    for (int k = 0; k < 25; ++k) p[4 * k] = m[k] * inv;
    __syncthreads();

    for (int e4 = tid; e4 < 1600; e4 += 256)
        ((float4*)gp)[e4] = ((const float4*)L)[e4];
}

// ---------------- K3 v4: reassembly (masks pre-normalized) --------------
// grid 1024 x 256thr: b = cchunk*64 + tile. 16x16 px tile, 16-c chunk.
// x tile in LDS as [cg8][r20][q20][2]; one ds_read_b64 per tap serves 2
// channels. Taps OUTER, channels inner; resident float2 A[8][4] (64 VGPR,
// statically indexed). Plain launch_bounds(256) (min-waves hint spills).
__global__ __launch_bounds__(256) void k3_out(const float* __restrict__ x,
                                              const float* __restrict__ logits,
                                              float* __restrict__ out) {
    __shared__ __align__(16) float xt[8 * 20 * 42];  // 26880 B
    int b      = blockIdx.x;
    int tile   = b & 63;
    int cchunk = b >> 6;
    int n = tile >> 4, ty0 = ((tile >> 2) & 3) * 16, tx0 = (tile & 3) * 16;
    int c0 = cchunk * 16;

    int py = threadIdx.x >> 4, pxx = threadIdx.x & 15;
    int h = ty0 + py, w = tx0 + pxx;

    // stage x halo tile as float2 (halo col origin tx0-2 is even -> the
    // 20-wide row is 10 aligned float2s, all-or-nothing in bounds).
    const float* xn = x + (size_t)(n * 256 + c0) * 4096;
    for (int e2 = threadIdx.x; e2 < 3200; e2 += 256) {
        int c = e2 / 200, rem = e2 % 200, r = rem / 10, q2 = rem % 10;
        int hh = ty0 + r - 2, ww = tx0 + 2 * q2 - 2;
        float2 v = {0.f, 0.f};
        if (hh >= 0 && hh < 64 && ww >= 0 && ww < 64)
            v = *(const float2*)(xn + (size_t)c * 4096 + hh * 64 + ww);
        int a0 = (c >> 1) * 840 + r * 42 + 4 * q2 + (c & 1);
        xt[a0]     = v.x;
        xt[a0 + 2] = v.y;
    }
    __syncthreads();

    const float* lp = logits + (size_t)(n * 4096 + h * 64 + w) * 100;
    const float* vb = xt + py * 42 + pxx * 2;

    float2 A[8][4];
#pragma unroll
    for (int cg = 0; cg < 8; ++cg)
#pragma unroll
        for (int u = 0; u < 4; ++u) A[cg][u] = {0.f, 0.f};

    for (int dy = 0; dy < 5; ++dy) {
        const float4* mkp = (const float4*)lp + dy * 5;  // 5 taps this row
        const float* vrow = vb + dy * 42;
#pragma unroll
        for (int dx = 0; dx < 5; ++dx) {
            float4 mk = mkp[dx];                         // transient, L2-hot
#pragma unroll
            for (int cg = 0; cg < 8; ++cg) {
                float2 v = *(const float2*)(vrow + cg * 840 + dx * 2);
                A[cg][0].x += v.x * mk.x; A[cg][0].y += v.y * mk.x;
                A[cg][1].x += v.x * mk.y; A[cg][1].y += v.y * mk.y;
                A[cg][2].x += v.x * mk.z; A[cg][2].y += v.y * mk.z;
                A[cg][3].x += v.x * mk.w; A[cg][3].y += v.y * mk.w;
            }
        }
    }

#pragma unroll
    for (int cg = 0; cg < 8; ++cg) {
        int c = cg * 2;
        size_t ob0 = (((size_t)(n * 256 + c0 + c) * 128) + 2 * h) * 128 + 2 * w;
        float2 r0 = {A[cg][0].x, A[cg][1].x}, r1 = {A[cg][2].x, A[cg][3].x};
        *(float2*)(out + ob0)       = r0;
        *(float2*)(out + ob0 + 128) = r1;
        size_t ob1 = ob0 + 16384;
        float2 r2 = {A[cg][0].y, A[cg][1].y}, r3 = {A[cg][2].y, A[cg][3].y};
        *(float2*)(out + ob1)       = r2;
        *(float2*)(out + ob1 + 128) = r3;
    }
}

// ---------------- Fallback: fused kernel, fp32-only ---------------------
__global__ __launch_bounds__(256) void k_fused(const float* __restrict__ x,
                                               const float* __restrict__ Wc,
                                               const float* __restrict__ bc,
                                               const float* __restrict__ We,
                                               const float* __restrict__ be,
                                               float* __restrict__ out) {
    __shared__ float compS[64 * 101];
    int n = blockIdx.x >> 6, tile = blockIdx.x & 63;
    int ty0 = (tile >> 3) * 8, tx0 = (tile & 7) * 8;
    const float* xn = x + (size_t)n * 256 * 4096;
    {
        int pa = threadIdx.x & 127;
        int ga = __builtin_amdgcn_readfirstlane(threadIdx.x >> 7);
        bool act = pa < 100;
        int ah = ty0 + pa / 10 - 1, aw = tx0 + pa % 10 - 1;
        bool inb = act && ah >= 0 && ah < 64 && aw >= 0 && aw < 64;
        int xoff = ah * 64 + aw;
        float acc[32];
#pragma unroll
        for (int i = 0; i < 32; ++i) acc[i] = 0.f;
        for (int c = 0; c < 256; ++c) {
            float xv = inb ? xn[(size_t)c * 4096 + xoff] : 0.f;
#pragma unroll
            for (int i = 0; i < 32; ++i) acc[i] += xv * Wc[(ga * 32 + i) * 256 + c];
        }
        if (act)
#pragma unroll
            for (int i = 0; i < 32; ++i) {
                int cc = ga * 32 + i;
                compS[cc * 101 + pa] = inb ? acc[i] + bc[cc] : 0.f;
            }
    }
    __syncthreads();
    int px = threadIdx.x & 63;
    int ij = __builtin_amdgcn_readfirstlane(threadIdx.x >> 6);
    int py = px >> 3, pxx = px & 7;
    int h = ty0 + py, w = tx0 + pxx;
    float m[25];
#pragma unroll
    for (int k = 0; k < 25; ++k) m[k] = be[4 * k + ij];
    for (int cc = 0; cc < 64; ++cc) {
        float cv[9];
#pragma unroll
        for (int dy = 0; dy < 3; ++dy)
#pragma unroll
            for (int dx = 0; dx < 3; ++dx)
                cv[dy * 3 + dx] = compS[cc * 101 + (py + dy) * 10 + (pxx + dx)];
        int base = cc * 9;
#pragma unroll
        for (int k = 0; k < 25; ++k) {
            int eb = (4 * k + ij) * 576 + base;
            float s = 0.f;
#pragma unroll
            for (int qb = 0; qb < 9; ++qb) s += cv[qb] * We[eb + qb];
            m[k] += s;
        }
    }
    float mxv = m[0];
#pragma unroll
    for (int k = 1; k < 25; ++k) mxv = fmaxf(mxv, m[k]);
    float ss = 0.f;
#pragma unroll
    for (int k = 0; k < 25; ++k) { m[k] = __expf(m[k] - mxv); ss += m[k]; }
    float inv = 1.f / ss;
#pragma unroll
    for (int k = 0; k < 25; ++k) m[k] *= inv;
    int offs[25];
    unsigned vm = 0;
#pragma unroll
    for (int t = 0; t < 25; ++t) {
        int hh = h + t / 5 - 2, ww = w + t % 5 - 2;
        bool v = hh >= 0 && hh < 64 && ww >= 0 && ww < 64;
        offs[t] = v ? hh * 64 + ww : 0;
        if (v) vm |= 1u << t;
    }
    size_t outp = ((size_t)n * 256 * 128 + (2 * h + (ij >> 1))) * 128 + (2 * w + (ij & 1));
    for (int c = 0; c < 256; ++c) {
        const float* xc = xn + (size_t)c * 4096;
        float sum = 0.f;
#pragma unroll
        for (int t = 0; t < 25; ++t) {
            float v = ((vm >> t) & 1u) ? xc[offs[t]] : 0.f;
            sum += v * m[t];
        }
        out[outp + (size_t)c * 16384] = sum;
    }
}

extern "C" void kernel_launch(void* const* d_in, const int* in_sizes, int n_in,
                              void* d_out, int out_size, void* d_ws, size_t ws_size,
                              hipStream_t stream) {
    const float* x  = (const float*)d_in[0];
    const float* Wc = (const float*)d_in[1];
    const float* bc = (const float*)d_in[2];
    const float* We = (const float*)d_in[3];
    const float* be = (const float*)d_in[4];
    float* out = (float*)d_out;

    if (ws_size >= WS_NEED && d_ws != nullptr) {
        float* ws = (float*)d_ws;
        float* comp   = ws + COMP_F;
        float* wr     = ws + WR_F;
        float* logits = ws + LOG_F;
        hipLaunchKernelGGL(k0_wr,   dim3(289),  dim3(256), 0, stream, We, Wc, ws);
        hipLaunchKernelGGL(k1_comp, dim3(512),  dim3(256), 0, stream,
                           x, bc, /*wT=*/logits, comp);
        hipLaunchKernelGGL(k2_enc,  dim3(1280), dim3(512), 0, stream,
                           be, comp, wr, logits);
        hipLaunchKernelGGL(k2s_sm,  dim3(256),  dim3(256), 0, stream, logits);
        hipLaunchKernelGGL(k3_out,  dim3(1024), dim3(256), 0, stream,
                           x, logits, out);
    } else {
        hipLaunchKernelGGL(k_fused, dim3(256),  dim3(256), 0, stream,
                           x, Wc, bc, We, be, out);
    }
}

// Round 14
// 176.503 us; speedup vs baseline: 1.8029x; 1.0310x over previous
//
#include <hip/hip_runtime.h>
#include <hip/hip_bf16.h>

// CARAFE fp32 pipeline. x(4,256,64,64), Wc(64,256), bc(64), We(100,64,3,3),
// be(100) -> out(4,256,128,128). SF=2 K=5 G=1 CC=64 EK=3. All I/O fp32.
//
// ws layout (fp32 elements):
//   comp  [4][64][66*66]   zero-padded halo   @ 0          (1,115,136)
//   Wr2   [ij4][kt5][cc64][48]  q*5+kk packed @ 1,115,136  (61,440 of 64,512)
//   logit [16384 px][100]  e = 4k+ij          @ 1,179,648  (1,638,400)
//     NB: first 16,384 floats of logit double as WcT[c256][cc64] during
//     k0->k1 (dead until k2 overwrites logits; stream-serialized).
// total 11,272,192 B. Host-gated on ws_size; fallback = fused kernel.
//
// Round 17 (this round): REVERT k2 to the v7 shell (v9's 8-wave reduce
// regressed 49.2->54.1: occupancy only 50%, barrier+reduce overhead) and
// fix the ACTUAL invariant cost. Evidence across 7 variants: VALU-issue
// ~2.3x pure FMA, duration ~invariant. Mechanism: s_load (weights) and
// ds_read (cv) share lgkmcnt; SMEM is out-of-order -> compiler must
// lgkmcnt(0) before EVERY 45-FMA block -> one full drain-stall per
// channel, immune to occupancy/bank tuning. v10: manual 2-channel unroll
// -- issue all 18 cv ds_reads, then 90 FMAs -> one drain per TWO channels
// (64->32 drains/wave). Split accumulators (accA even / accB odd) halve
// the dependent-FMA chain depth. No geometry/LDS/occupancy change.

#define COMP_F 0
#define WR_F   1115136
#define LOG_F  1179648
#define WS_NEED 11272192ull
#define CSTR 4356  // 66*66 comp per-channel stride

// ---------------- K0: Wr2 repack + WcT transpose ------------------------
// job1 (tid < 57600): We(100,576) -> Wr2[ij][kt][cc][48], row = q*5+kk.
// job2 (tid >= 57600): Wc(64,256) -> WcT[c][cc] @ LOG_F (16,384 floats).
__global__ void k0_wr(const float* __restrict__ We, const float* __restrict__ Wc,
                      float* __restrict__ ws) {
    int tid = blockIdx.x * blockDim.x + threadIdx.x;
    if (tid < 57600) {
        int kk = tid % 5;
        int q  = (tid / 5) % 9;
        int cc = (tid / 45) % 64;
        int kt = (tid / 2880) % 5;
        int ij = tid / 14400;
        ws[WR_F + (size_t)(((ij * 5 + kt) * 64 + cc)) * 48 + q * 5 + kk] =
            We[(size_t)(4 * (kt * 5 + kk) + ij) * 576 + cc * 9 + q];
    } else if (tid < 57600 + 16384) {
        int t2 = tid - 57600;
        int c = t2 >> 6, cc = t2 & 63;
        ws[LOG_F + t2] = Wc[cc * 256 + c];
    }
}

// ---------------- K1 v4: 1x1 compressor 256->64, padded comp out --------
// grid 512 = ccq*64 + pxtile; block 256thr; thread = one pixel, 8 cc.
// Weights from WcT via s_load_dwordx8 (restrict args). Coalesced x loads.
__global__ __launch_bounds__(256) void k1_comp(const float* __restrict__ x,
                                               const float* __restrict__ bc,
                                               const float* __restrict__ wT,
                                               float* __restrict__ comp) {
    int b      = blockIdx.x;
    int pxtile = b & 63;       // 0..63 ; b%8 = pxtile%8 -> cc-siblings same XCD
    int ccq    = b >> 6;       // 0..7, wave-uniform
    int tid = threadIdx.x;
    int n   = pxtile >> 4;
    int off = (pxtile & 15) * 256 + tid;   // 0..4095 within image
    int h = off >> 6, w = off & 63;
    int cc0 = ccq * 8;

    const float* xp = x + (size_t)n * 256 * 4096 + off;

    float acc[8];
#pragma unroll
    for (int u = 0; u < 8; ++u) acc[u] = 0.f;

#pragma unroll 8
    for (int c = 0; c < 256; ++c) {
        float xv = xp[(size_t)c * 4096];
        const float* wr = wT + c * 64 + cc0;   // uniform -> s_load_dwordx8
#pragma unroll
        for (int u = 0; u < 8; ++u) acc[u] += xv * wr[u];
    }

    float* compb = comp + (size_t)(n * 64 + cc0) * CSTR;
#pragma unroll
    for (int u = 0; u < 8; ++u) {
        float* cb_ = compb + (size_t)u * CSTR;
        cb_[(h + 1) * 66 + (w + 1)] = acc[u] + bc[cc0 + u];
        // zero halo border (pad=1 of the 3x3 conv)
        if (w < 2) cb_[(h + 1) * 66 + (w ? 65 : 0)] = 0.f;
        if (h == 0)  { cb_[w] = 0.f;           if (w < 2) cb_[64 + w] = 0.f; }
        if (h == 63) { cb_[65 * 66 + w] = 0.f; if (w < 2) cb_[65 * 66 + 64 + w] = 0.f; }
    }
}

// ---------------- K2 v10: 3x3 encoder, 2-channel drain amortization -----
// Shell = v7 (grid 1280 = kt*256 + tile; block 256 thr = 4 ij-waves;
// comp tile in LDS stride 12; conflict-free lane map; SGPR weights;
// (256,5) bounds, 5 blocks/CU). Inner loop: channels in PAIRS -- 18
// ds_reads issued up front, then 90 FMAs -> one lgkmcnt drain per 2
// channels (the drain was the invariant per-channel cost). accA/accB
// split by parity halves the dependent-FMA chain depth; merged at store.
__global__ __launch_bounds__(256, 5) void k2_enc(const float* __restrict__ be,
                                                 const float* __restrict__ comp,
                                                 const float* __restrict__ wr,
                                                 float* __restrict__ logits) {
    __shared__ __align__(16) float compT[64 * 120];  // 30720 B
    int b    = blockIdx.x;
    int tile = b & 255;                              // low bits: same-tile
    int kt   = b >> 8;                               // 0..4, siblings same XCD
    int n = tile >> 6, th = (tile >> 3) & 7, tw = tile & 7;
    int h0 = th * 8, w0 = tw * 8;
    int tid = threadIdx.x;

    const float* compn = comp + (size_t)n * 64 * CSTR;
    // stage comp halo tile: compT[c*120 + r*12 + q] = comp[c][h0+r][w0+q]
    for (int e = tid; e < 6400; e += 256) {
        int c = e / 100, rq = e % 100, r = rq / 10, q = rq % 10;
        compT[c * 120 + r * 12 + q] =
            compn[(size_t)c * CSTR + (h0 + r) * 66 + (w0 + q)];
    }
    __syncthreads();

    int lane = tid & 63;
    int ij   = __builtin_amdgcn_readfirstlane(tid >> 6);  // force scalar
    int py = lane & 7, pxx = lane >> 3;   // conflict-free bank walk (r13)

    const float* wb = wr + (size_t)((ij * 5 + kt) * 64) * 48;

    float accA[5], accB[5];
#pragma unroll
    for (int kk = 0; kk < 5; ++kk) {
        accA[kk] = be[4 * (kt * 5 + kk) + ij];
        accB[kk] = 0.f;
    }

    for (int c = 0; c < 64; c += 2) {
        const float* cp = compT + c * 120 + py * 12 + pxx;
        float cv0[9], cv1[9];
#pragma unroll
        for (int dy = 0; dy < 3; ++dy)
#pragma unroll
            for (int dx = 0; dx < 3; ++dx) {
                cv0[dy * 3 + dx] = cp[dy * 12 + dx];
                cv1[dy * 3 + dx] = cp[120 + dy * 12 + dx];
            }
        const float* w0 = wb + c * 48;               // uniform -> s_load
        const float* w1 = w0 + 48;
#pragma unroll
        for (int q = 0; q < 9; ++q) {
            float v0 = cv0[q], v1 = cv1[q];
#pragma unroll
            for (int kk = 0; kk < 5; ++kk) {
                accA[kk] += v0 * w0[q * 5 + kk];     // v_fmac v, s, v
                accB[kk] += v1 * w1[q * 5 + kk];
            }
        }
    }

    float* lp = logits +
                (size_t)(n * 4096 + (h0 + py) * 64 + (w0 + pxx)) * 100 + ij;
#pragma unroll
    for (int kk = 0; kk < 5; ++kk)
        lp[4 * (kt * 5 + kk)] = accA[kk] + accB[kk];
}

// ---------------- K2s v2: in-place softmax, LDS-coalesced ---------------
// grid 256 x 256thr: block handles 64 px. Coalesced float4 I/O through
// LDS. Softmax thread-task = (pxl, ij); LDS reads at pxl*100+4k+ij are
// 2-way bank aliased max (100 mod 32 = 4) = free.
__global__ __launch_bounds__(256) void k2s_sm(float* __restrict__ logits) {
    __shared__ __align__(16) float L[64 * 100];  // 25600 B
    float* gp = logits + (size_t)blockIdx.x * 6400;
    int tid = threadIdx.x;

    for (int e4 = tid; e4 < 1600; e4 += 256)
        ((float4*)L)[e4] = ((const float4*)gp)[e4];
    __syncthreads();

    int pxl = tid >> 2, ij = tid & 3;
    float* p = L + pxl * 100 + ij;
    float m[25];
#pragma unroll
    for (int k = 0; k < 25; ++k) m[k] = p[4 * k];
    float mx = m[0];
#pragma unroll
    for (int k = 1; k < 25; ++k) mx = fmaxf(mx, m[k]);
    float ss = 0.f;
#pragma unroll
    for (int k = 0; k < 25; ++k) { m[k] = __expf(m[k] - mx); ss += m[k]; }
    float inv = 1.f / ss;
#pragma unroll
    for (int k = 0; k < 25; ++k) p[4 * k] = m[k] * inv;
    __syncthreads();

    for (int e4 = tid; e4 < 1600; e4 += 256)
        ((float4*)gp)[e4] = ((const float4*)L)[e4];
}

// ---------------- K3 v4: reassembly (masks pre-normalized) --------------
// grid 1024 x 256thr: b = cchunk*64 + tile. 16x16 px tile, 16-c chunk.
// x tile in LDS as [cg8][r20][q20][2]; one ds_read_b64 per tap serves 2
// channels. Taps OUTER, channels inner; resident float2 A[8][4] (64 VGPR,
// statically indexed). Plain launch_bounds(256) (min-waves hint spills).
__global__ __launch_bounds__(256) void k3_out(const float* __restrict__ x,
                                              const float* __restrict__ logits,
                                              float* __restrict__ out) {
    __shared__ __align__(16) float xt[8 * 20 * 42];  // 26880 B
    int b      = blockIdx.x;
    int tile   = b & 63;
    int cchunk = b >> 6;
    int n = tile >> 4, ty0 = ((tile >> 2) & 3) * 16, tx0 = (tile & 3) * 16;
    int c0 = cchunk * 16;

    int py = threadIdx.x >> 4, pxx = threadIdx.x & 15;
    int h = ty0 + py, w = tx0 + pxx;

    // stage x halo tile as float2 (halo col origin tx0-2 is even -> the
    // 20-wide row is 10 aligned float2s, all-or-nothing in bounds).
    const float* xn = x + (size_t)(n * 256 + c0) * 4096;
    for (int e2 = threadIdx.x; e2 < 3200; e2 += 256) {
        int c = e2 / 200, rem = e2 % 200, r = rem / 10, q2 = rem % 10;
        int hh = ty0 + r - 2, ww = tx0 + 2 * q2 - 2;
        float2 v = {0.f, 0.f};
        if (hh >= 0 && hh < 64 && ww >= 0 && ww < 64)
            v = *(const float2*)(xn + (size_t)c * 4096 + hh * 64 + ww);
        int a0 = (c >> 1) * 840 + r * 42 + 4 * q2 + (c & 1);
        xt[a0]     = v.x;
        xt[a0 + 2] = v.y;
    }
    __syncthreads();

    const float* lp = logits + (size_t)(n * 4096 + h * 64 + w) * 100;
    const float* vb = xt + py * 42 + pxx * 2;

    float2 A[8][4];
#pragma unroll
    for (int cg = 0; cg < 8; ++cg)
#pragma unroll
        for (int u = 0; u < 4; ++u) A[cg][u] = {0.f, 0.f};

    for (int dy = 0; dy < 5; ++dy) {
        const float4* mkp = (const float4*)lp + dy * 5;  // 5 taps this row
        const float* vrow = vb + dy * 42;
#pragma unroll
        for (int dx = 0; dx < 5; ++dx) {
            float4 mk = mkp[dx];                         // transient, L2-hot
#pragma unroll
            for (int cg = 0; cg < 8; ++cg) {
                float2 v = *(const float2*)(vrow + cg * 840 + dx * 2);
                A[cg][0].x += v.x * mk.x; A[cg][0].y += v.y * mk.x;
                A[cg][1].x += v.x * mk.y; A[cg][1].y += v.y * mk.y;
                A[cg][2].x += v.x * mk.z; A[cg][2].y += v.y * mk.z;
                A[cg][3].x += v.x * mk.w; A[cg][3].y += v.y * mk.w;
            }
        }
    }

#pragma unroll
    for (int cg = 0; cg < 8; ++cg) {
        int c = cg * 2;
        size_t ob0 = (((size_t)(n * 256 + c0 + c) * 128) + 2 * h) * 128 + 2 * w;
        float2 r0 = {A[cg][0].x, A[cg][1].x}, r1 = {A[cg][2].x, A[cg][3].x};
        *(float2*)(out + ob0)       = r0;
        *(float2*)(out + ob0 + 128) = r1;
        size_t ob1 = ob0 + 16384;
        float2 r2 = {A[cg][0].y, A[cg][1].y}, r3 = {A[cg][2].y, A[cg][3].y};
        *(float2*)(out + ob1)       = r2;
        *(float2*)(out + ob1 + 128) = r3;
    }
}

// ---------------- Fallback: fused kernel, fp32-only ---------------------
__global__ __launch_bounds__(256) void k_fused(const float* __restrict__ x,
                                               const float* __restrict__ Wc,
                                               const float* __restrict__ bc,
                                               const float* __restrict__ We,
                                               const float* __restrict__ be,
                                               float* __restrict__ out) {
    __shared__ float compS[64 * 101];
    int n = blockIdx.x >> 6, tile = blockIdx.x & 63;
    int ty0 = (tile >> 3) * 8, tx0 = (tile & 7) * 8;
    const float* xn = x + (size_t)n * 256 * 4096;
    {
        int pa = threadIdx.x & 127;
        int ga = __builtin_amdgcn_readfirstlane(threadIdx.x >> 7);
        bool act = pa < 100;
        int ah = ty0 + pa / 10 - 1, aw = tx0 + pa % 10 - 1;
        bool inb = act && ah >= 0 && ah < 64 && aw >= 0 && aw < 64;
        int xoff = ah * 64 + aw;
        float acc[32];
#pragma unroll
        for (int i = 0; i < 32; ++i) acc[i] = 0.f;
        for (int c = 0; c < 256; ++c) {
            float xv = inb ? xn[(size_t)c * 4096 + xoff] : 0.f;
#pragma unroll
            for (int i = 0; i < 32; ++i) acc[i] += xv * Wc[(ga * 32 + i) * 256 + c];
        }
        if (act)
#pragma unroll
            for (int i = 0; i < 32; ++i) {
                int cc = ga * 32 + i;
                compS[cc * 101 + pa] = inb ? acc[i] + bc[cc] : 0.f;
            }
    }
    __syncthreads();
    int px = threadIdx.x & 63;
    int ij = __builtin_amdgcn_readfirstlane(threadIdx.x >> 6);
    int py = px >> 3, pxx = px & 7;
    int h = ty0 + py, w = tx0 + pxx;
    float m[25];
#pragma unroll
    for (int k = 0; k < 25; ++k) m[k] = be[4 * k + ij];
    for (int cc = 0; cc < 64; ++cc) {
        float cv[9];
#pragma unroll
        for (int dy = 0; dy < 3; ++dy)
#pragma unroll
            for (int dx = 0; dx < 3; ++dx)
                cv[dy * 3 + dx] = compS[cc * 101 + (py + dy) * 10 + (pxx + dx)];
        int base = cc * 9;
#pragma unroll
        for (int k = 0; k < 25; ++k) {
            int eb = (4 * k + ij) * 576 + base;
            float s = 0.f;
#pragma unroll
            for (int qb = 0; qb < 9; ++qb) s += cv[qb] * We[eb + qb];
            m[k] += s;
        }
    }
    float mxv = m[0];
#pragma unroll
    for (int k = 1; k < 25; ++k) mxv = fmaxf(mxv, m[k]);
    float ss = 0.f;
#pragma unroll
    for (int k = 0; k < 25; ++k) { m[k] = __expf(m[k] - mxv); ss += m[k]; }
    float inv = 1.f / ss;
#pragma unroll
    for (int k = 0; k < 25; ++k) m[k] *= inv;
    int offs[25];
    unsigned vm = 0;
#pragma unroll
    for (int t = 0; t < 25; ++t) {
        int hh = h + t / 5 - 2, ww = w + t % 5 - 2;
        bool v = hh >= 0 && hh < 64 && ww >= 0 && ww < 64;
        offs[t] = v ? hh * 64 + ww : 0;
        if (v) vm |= 1u << t;
    }
    size_t outp = ((size_t)n * 256 * 128 + (2 * h + (ij >> 1))) * 128 + (2 * w + (ij & 1));
    for (int c = 0; c < 256; ++c) {
        const float* xc = xn + (size_t)c * 4096;
        float sum = 0.f;
#pragma unroll
        for (int t = 0; t < 25; ++t) {
            float v = ((vm >> t) & 1u) ? xc[offs[t]] : 0.f;
            sum += v * m[t];
        }
        out[outp + (size_t)c * 16384] = sum;
    }
}

extern "C" void kernel_launch(void* const* d_in, const int* in_sizes, int n_in,
                              void* d_out, int out_size, void* d_ws, size_t ws_size,
                              hipStream_t stream) {
    const float* x  = (const float*)d_in[0];
    const float* Wc = (const float*)d_in[1];
    const float* bc = (const float*)d_in[2];
    const float* We = (const float*)d_in[3];
    const float* be = (const float*)d_in[4];
    float* out = (float*)d_out;

    if (ws_size >= WS_NEED && d_ws != nullptr) {
        float* ws = (float*)d_ws;
        float* comp   = ws + COMP_F;
        float* wr     = ws + WR_F;
        float* logits = ws + LOG_F;
        hipLaunchKernelGGL(k0_wr,   dim3(289),  dim3(256), 0, stream, We, Wc, ws);
        hipLaunchKernelGGL(k1_comp, dim3(512),  dim3(256), 0, stream,
                           x, bc, /*wT=*/logits, comp);
        hipLaunchKernelGGL(k2_enc,  dim3(1280), dim3(256), 0, stream,
                           be, comp, wr, logits);
        hipLaunchKernelGGL(k2s_sm,  dim3(256),  dim3(256), 0, stream, logits);
        hipLaunchKernelGGL(k3_out,  dim3(1024), dim3(256), 0, stream,
                           x, logits, out);
    } else {
        hipLaunchKernelGGL(k_fused, dim3(256),  dim3(256), 0, stream,
                           x, Wc, bc, We, be, out);
    }
}

// Round 15
// 176.408 us; speedup vs baseline: 1.8038x; 1.0005x over previous
//
#include <hip/hip_runtime.h>
#include <hip/hip_bf16.h>

// CARAFE fp32 pipeline. x(4,256,64,64), Wc(64,256), bc(64), We(100,64,3,3),
// be(100) -> out(4,256,128,128). SF=2 K=5 G=1 CC=64 EK=3. All I/O fp32.
//
// ws layout (fp32 elements):
//   comp  [4][64][66*66]   zero-padded halo   @ 0          (1,115,136)
//   Wr2   [ij4][kt5][cc64][48]  q*5+kk packed @ 1,115,136  (61,440 of 64,512)
//   logit [tile256][e100][off64]  TILE-MAJOR  @ 1,179,648  (1,638,400)
//     tile = n*64 + th*8 + tw (8x8-px k2 tiles), off = (h&7)*8 + (w&7).
//     NB: first 16,384 floats double as WcT[c256][cc64] during k0->k1
//     (k2 overwrites tiles 0..2 later; stream-serialized).
// total 11,272,192 B. Host-gated on ws_size; fallback = fused kernel.
//
// Round 18 (this round): TILE-MAJOR LOGITS. Accounting: k3 ~= 43us (r4->r5
// delta), just under k2's 47 in every top-5. Old [px][100] layout put
// consecutive threads 400B apart: k3's 25 float4 mask loads each split
// into 64x64B transactions (~25% of k3); k2's 5 stores scatter the same
// way (~6% of k2). New layout: k2 stores hit one contiguous 256B block
// (off is a lane bijection); k3 reads 4 scalars/tap in 2x128B segments;
// k2s tiles stay fully contiguous. No other changes from the 176.5 best.

#define COMP_F 0
#define WR_F   1115136
#define LOG_F  1179648
#define WS_NEED 11272192ull
#define CSTR 4356  // 66*66 comp per-channel stride

// ---------------- K0: Wr2 repack + WcT transpose ------------------------
// job1 (tid < 57600): We(100,576) -> Wr2[ij][kt][cc][48], row = q*5+kk.
// job2 (tid >= 57600): Wc(64,256) -> WcT[c][cc] @ LOG_F (16,384 floats).
__global__ void k0_wr(const float* __restrict__ We, const float* __restrict__ Wc,
                      float* __restrict__ ws) {
    int tid = blockIdx.x * blockDim.x + threadIdx.x;
    if (tid < 57600) {
        int kk = tid % 5;
        int q  = (tid / 5) % 9;
        int cc = (tid / 45) % 64;
        int kt = (tid / 2880) % 5;
        int ij = tid / 14400;
        ws[WR_F + (size_t)(((ij * 5 + kt) * 64 + cc)) * 48 + q * 5 + kk] =
            We[(size_t)(4 * (kt * 5 + kk) + ij) * 576 + cc * 9 + q];
    } else if (tid < 57600 + 16384) {
        int t2 = tid - 57600;
        int c = t2 >> 6, cc = t2 & 63;
        ws[LOG_F + t2] = Wc[cc * 256 + c];
    }
}

// ---------------- K1 v4: 1x1 compressor 256->64, padded comp out --------
// grid 512 = ccq*64 + pxtile; block 256thr; thread = one pixel, 8 cc.
// Weights from WcT via s_load_dwordx8 (restrict args). Coalesced x loads.
__global__ __launch_bounds__(256) void k1_comp(const float* __restrict__ x,
                                               const float* __restrict__ bc,
                                               const float* __restrict__ wT,
                                               float* __restrict__ comp) {
    int b      = blockIdx.x;
    int pxtile = b & 63;       // 0..63 ; b%8 = pxtile%8 -> cc-siblings same XCD
    int ccq    = b >> 6;       // 0..7, wave-uniform
    int tid = threadIdx.x;
    int n   = pxtile >> 4;
    int off = (pxtile & 15) * 256 + tid;   // 0..4095 within image
    int h = off >> 6, w = off & 63;
    int cc0 = ccq * 8;

    const float* xp = x + (size_t)n * 256 * 4096 + off;

    float acc[8];
#pragma unroll
    for (int u = 0; u < 8; ++u) acc[u] = 0.f;

#pragma unroll 8
    for (int c = 0; c < 256; ++c) {
        float xv = xp[(size_t)c * 4096];
        const float* wr = wT + c * 64 + cc0;   // uniform -> s_load_dwordx8
#pragma unroll
        for (int u = 0; u < 8; ++u) acc[u] += xv * wr[u];
    }

    float* compb = comp + (size_t)(n * 64 + cc0) * CSTR;
#pragma unroll
    for (int u = 0; u < 8; ++u) {
        float* cb_ = compb + (size_t)u * CSTR;
        cb_[(h + 1) * 66 + (w + 1)] = acc[u] + bc[cc0 + u];
        // zero halo border (pad=1 of the 3x3 conv)
        if (w < 2) cb_[(h + 1) * 66 + (w ? 65 : 0)] = 0.f;
        if (h == 0)  { cb_[w] = 0.f;           if (w < 2) cb_[64 + w] = 0.f; }
        if (h == 63) { cb_[65 * 66 + w] = 0.f; if (w < 2) cb_[65 * 66 + 64 + w] = 0.f; }
    }
}

// ---------------- K2 v11: 3x3 encoder -> tile-major logits --------------
// = v10 (2-channel drain amortization, conflict-free lane map, SGPR
// weights, grid 1280, (256,5)) with coalesced tile-major stores:
// lp = logit + tile*6400 + off, store at lp[e*64]. off=(lane&7)*8+
// (lane>>3) is a lane bijection -> each store = one 256B block.
__global__ __launch_bounds__(256, 5) void k2_enc(const float* __restrict__ be,
                                                 const float* __restrict__ comp,
                                                 const float* __restrict__ wr,
                                                 float* __restrict__ logits) {
    __shared__ __align__(16) float compT[64 * 120];  // 30720 B
    int b    = blockIdx.x;
    int tile = b & 255;                              // = n*64 + th*8 + tw
    int kt   = b >> 8;                               // 0..4, siblings same XCD
    int n = tile >> 6, th = (tile >> 3) & 7, tw = tile & 7;
    int h0 = th * 8, w0 = tw * 8;
    int tid = threadIdx.x;

    const float* compn = comp + (size_t)n * 64 * CSTR;
    // stage comp halo tile: compT[c*120 + r*12 + q] = comp[c][h0+r][w0+q]
    for (int e = tid; e < 6400; e += 256) {
        int c = e / 100, rq = e % 100, r = rq / 10, q = rq % 10;
        compT[c * 120 + r * 12 + q] =
            compn[(size_t)c * CSTR + (h0 + r) * 66 + (w0 + q)];
    }
    __syncthreads();

    int lane = tid & 63;
    int ij   = __builtin_amdgcn_readfirstlane(tid >> 6);  // force scalar
    int py = lane & 7, pxx = lane >> 3;   // conflict-free bank walk (r13)

    const float* wb = wr + (size_t)((ij * 5 + kt) * 64) * 48;

    float accA[5], accB[5];
#pragma unroll
    for (int kk = 0; kk < 5; ++kk) {
        accA[kk] = be[4 * (kt * 5 + kk) + ij];
        accB[kk] = 0.f;
    }

    for (int c = 0; c < 64; c += 2) {
        const float* cp = compT + c * 120 + py * 12 + pxx;
        float cv0[9], cv1[9];
#pragma unroll
        for (int dy = 0; dy < 3; ++dy)
#pragma unroll
            for (int dx = 0; dx < 3; ++dx) {
                cv0[dy * 3 + dx] = cp[dy * 12 + dx];
                cv1[dy * 3 + dx] = cp[120 + dy * 12 + dx];
            }
        const float* w0 = wb + c * 48;               // uniform -> s_load
        const float* w1 = w0 + 48;
#pragma unroll
        for (int q = 0; q < 9; ++q) {
            float v0 = cv0[q], v1 = cv1[q];
#pragma unroll
            for (int kk = 0; kk < 5; ++kk) {
                accA[kk] += v0 * w0[q * 5 + kk];     // v_fmac v, s, v
                accB[kk] += v1 * w1[q * 5 + kk];
            }
        }
    }

    // tile-major store: one contiguous 256B block per e-plane.
    float* lp = logits + (size_t)tile * 6400 + (py * 8 + pxx);
#pragma unroll
    for (int kk = 0; kk < 5; ++kk)
        lp[(4 * (kt * 5 + kk) + ij) * 64] = accA[kk] + accB[kk];
}

// ---------------- K2s v4: in-place softmax, tile-major ------------------
// grid 256 x 256thr: block = one 8x8 tile (6400 contiguous floats).
// Coalesced float4 stage/unstage. Thread = (ij = tid>>6, off = tid&63):
// reads L[(4k+ij)*64 + off] stride 256 -> bank = off%32, lanes off 0..63
// -> 2-way alias = free.
__global__ __launch_bounds__(256) void k2s_sm(float* __restrict__ logits) {
    __shared__ __align__(16) float L[6400];  // 25600 B
    float* gp = logits + (size_t)blockIdx.x * 6400;
    int tid = threadIdx.x;

    for (int e4 = tid; e4 < 1600; e4 += 256)
        ((float4*)L)[e4] = ((const float4*)gp)[e4];
    __syncthreads();

    int ij = tid >> 6, off = tid & 63;
    float* p = L + ij * 64 + off;
    float m[25];
#pragma unroll
    for (int k = 0; k < 25; ++k) m[k] = p[k * 256];
    float mx = m[0];
#pragma unroll
    for (int k = 1; k < 25; ++k) mx = fmaxf(mx, m[k]);
    float ss = 0.f;
#pragma unroll
    for (int k = 0; k < 25; ++k) { m[k] = __expf(m[k] - mx); ss += m[k]; }
    float inv = 1.f / ss;
#pragma unroll
    for (int k = 0; k < 25; ++k) p[k * 256] = m[k] * inv;
    __syncthreads();

    for (int e4 = tid; e4 < 1600; e4 += 256)
        ((float4*)gp)[e4] = ((const float4*)L)[e4];
}

// ---------------- K3 v5: reassembly, tile-major mask reads --------------
// grid 1024 x 256thr: b = cchunk*64 + tile16. 16x16 px tile, 16-c chunk.
// Masks: per tap, 4 scalar loads at mbase[(4t+ij)*64] -- each wave-load
// covers 2 contiguous 128B segments (was: float4 at 400B stride = 64
// transactions). x tile in LDS as [cg8][r20][q20][2] (unchanged).
__global__ __launch_bounds__(256) void k3_out(const float* __restrict__ x,
                                              const float* __restrict__ logits,
                                              float* __restrict__ out) {
    __shared__ __align__(16) float xt[8 * 20 * 42];  // 26880 B
    int b      = blockIdx.x;
    int tile16 = b & 63;
    int cchunk = b >> 6;
    int n = tile16 >> 4, ty0 = ((tile16 >> 2) & 3) * 16, tx0 = (tile16 & 3) * 16;
    int c0 = cchunk * 16;

    int py = threadIdx.x >> 4, pxx = threadIdx.x & 15;
    int h = ty0 + py, w = tx0 + pxx;

    // stage x halo tile as float2 (halo col origin tx0-2 is even -> the
    // 20-wide row is 10 aligned float2s, all-or-nothing in bounds).
    const float* xn = x + (size_t)(n * 256 + c0) * 4096;
    for (int e2 = threadIdx.x; e2 < 3200; e2 += 256) {
        int c = e2 / 200, rem = e2 % 200, r = rem / 10, q2 = rem % 10;
        int hh = ty0 + r - 2, ww = tx0 + 2 * q2 - 2;
        float2 v = {0.f, 0.f};
        if (hh >= 0 && hh < 64 && ww >= 0 && ww < 64)
            v = *(const float2*)(xn + (size_t)c * 4096 + hh * 64 + ww);
        int a0 = (c >> 1) * 840 + r * 42 + 4 * q2 + (c & 1);
        xt[a0]     = v.x;
        xt[a0 + 2] = v.y;
    }
    __syncthreads();

    // tile-major mask base for this thread's pixel
    int tileIdx = n * 64 + ((ty0 >> 3) + (py >> 3)) * 8 + (tx0 >> 3) + (pxx >> 3);
    int off     = (py & 7) * 8 + (pxx & 7);
    const float* mbase = logits + (size_t)tileIdx * 6400 + off;
    const float* vb = xt + py * 42 + pxx * 2;

    float2 A[8][4];
#pragma unroll
    for (int cg = 0; cg < 8; ++cg)
#pragma unroll
        for (int u = 0; u < 4; ++u) A[cg][u] = {0.f, 0.f};

    for (int dy = 0; dy < 5; ++dy) {
        const float* vrow = vb + dy * 42;
#pragma unroll
        for (int dx = 0; dx < 5; ++dx) {
            int t = dy * 5 + dx;
            const float* mp = mbase + 4 * t * 64;
            float4 mk = {mp[0], mp[64], mp[128], mp[192]};  // 4 coalesced scalars
#pragma unroll
            for (int cg = 0; cg < 8; ++cg) {
                float2 v = *(const float2*)(vrow + cg * 840 + dx * 2);
                A[cg][0].x += v.x * mk.x; A[cg][0].y += v.y * mk.x;
                A[cg][1].x += v.x * mk.y; A[cg][1].y += v.y * mk.y;
                A[cg][2].x += v.x * mk.z; A[cg][2].y += v.y * mk.z;
                A[cg][3].x += v.x * mk.w; A[cg][3].y += v.y * mk.w;
            }
        }
    }

#pragma unroll
    for (int cg = 0; cg < 8; ++cg) {
        int c = cg * 2;
        size_t ob0 = (((size_t)(n * 256 + c0 + c) * 128) + 2 * h) * 128 + 2 * w;
        float2 r0 = {A[cg][0].x, A[cg][1].x}, r1 = {A[cg][2].x, A[cg][3].x};
        *(float2*)(out + ob0)       = r0;
        *(float2*)(out + ob0 + 128) = r1;
        size_t ob1 = ob0 + 16384;
        float2 r2 = {A[cg][0].y, A[cg][1].y}, r3 = {A[cg][2].y, A[cg][3].y};
        *(float2*)(out + ob1)       = r2;
        *(float2*)(out + ob1 + 128) = r3;
    }
}

// ---------------- Fallback: fused kernel, fp32-only ---------------------
__global__ __launch_bounds__(256) void k_fused(const float* __restrict__ x,
                                               const float* __restrict__ Wc,
                                               const float* __restrict__ bc,
                                               const float* __restrict__ We,
                                               const float* __restrict__ be,
                                               float* __restrict__ out) {
    __shared__ float compS[64 * 101];
    int n = blockIdx.x >> 6, tile = blockIdx.x & 63;
    int ty0 = (tile >> 3) * 8, tx0 = (tile & 7) * 8;
    const float* xn = x + (size_t)n * 256 * 4096;
    {
        int pa = threadIdx.x & 127;
        int ga = __builtin_amdgcn_readfirstlane(threadIdx.x >> 7);
        bool act = pa < 100;
        int ah = ty0 + pa / 10 - 1, aw = tx0 + pa % 10 - 1;
        bool inb = act && ah >= 0 && ah < 64 && aw >= 0 && aw < 64;
        int xoff = ah * 64 + aw;
        float acc[32];
#pragma unroll
        for (int i = 0; i < 32; ++i) acc[i] = 0.f;
        for (int c = 0; c < 256; ++c) {
            float xv = inb ? xn[(size_t)c * 4096 + xoff] : 0.f;
#pragma unroll
            for (int i = 0; i < 32; ++i) acc[i] += xv * Wc[(ga * 32 + i) * 256 + c];
        }
        if (act)
#pragma unroll
            for (int i = 0; i < 32; ++i) {
                int cc = ga * 32 + i;
                compS[cc * 101 + pa] = inb ? acc[i] + bc[cc] : 0.f;
            }
    }
    __syncthreads();
    int px = threadIdx.x & 63;
    int ij = __builtin_amdgcn_readfirstlane(threadIdx.x >> 6);
    int py = px >> 3, pxx = px & 7;
    int h = ty0 + py, w = tx0 + pxx;
    float m[25];
#pragma unroll
    for (int k = 0; k < 25; ++k) m[k] = be[4 * k + ij];
    for (int cc = 0; cc < 64; ++cc) {
        float cv[9];
#pragma unroll
        for (int dy = 0; dy < 3; ++dy)
#pragma unroll
            for (int dx = 0; dx < 3; ++dx)
                cv[dy * 3 + dx] = compS[cc * 101 + (py + dy) * 10 + (pxx + dx)];
        int base = cc * 9;
#pragma unroll
        for (int k = 0; k < 25; ++k) {
            int eb = (4 * k + ij) * 576 + base;
            float s = 0.f;
#pragma unroll
            for (int qb = 0; qb < 9; ++qb) s += cv[qb] * We[eb + qb];
            m[k] += s;
        }
    }
    float mxv = m[0];
#pragma unroll
    for (int k = 1; k < 25; ++k) mxv = fmaxf(mxv, m[k]);
    float ss = 0.f;
#pragma unroll
    for (int k = 0; k < 25; ++k) { m[k] = __expf(m[k] - mxv); ss += m[k]; }
    float inv = 1.f / ss;
#pragma unroll
    for (int k = 0; k < 25; ++k) m[k] *= inv;
    int offs[25];
    unsigned vm = 0;
#pragma unroll
    for (int t = 0; t < 25; ++t) {
        int hh = h + t / 5 - 2, ww = w + t % 5 - 2;
        bool v = hh >= 0 && hh < 64 && ww >= 0 && ww < 64;
        offs[t] = v ? hh * 64 + ww : 0;
        if (v) vm |= 1u << t;
    }
    size_t outp = ((size_t)n * 256 * 128 + (2 * h + (ij >> 1))) * 128 + (2 * w + (ij & 1));
    for (int c = 0; c < 256; ++c) {
        const float* xc = xn + (size_t)c * 4096;
        float sum = 0.f;
#pragma unroll
        for (int t = 0; t < 25; ++t) {
            float v = ((vm >> t) & 1u) ? xc[offs[t]] : 0.f;
            sum += v * m[t];
        }
        out[outp + (size_t)c * 16384] = sum;
    }
}

extern "C" void kernel_launch(void* const* d_in, const int* in_sizes, int n_in,
                              void* d_out, int out_size, void* d_ws, size_t ws_size,
                              hipStream_t stream) {
    const float* x  = (const float*)d_in[0];
    const float* Wc = (const float*)d_in[1];
    const float* bc = (const float*)d_in[2];
    const float* We = (const float*)d_in[3];
    const float* be = (const float*)d_in[4];
    float* out = (float*)d_out;

    if (ws_size >= WS_NEED && d_ws != nullptr) {
        float* ws = (float*)d_ws;
        float* comp   = ws + COMP_F;
        float* wr     = ws + WR_F;
        float* logits = ws + LOG_F;
        hipLaunchKernelGGL(k0_wr,   dim3(289),  dim3(256), 0, stream, We, Wc, ws);
        hipLaunchKernelGGL(k1_comp, dim3(512),  dim3(256), 0, stream,
                           x, bc, /*wT=*/logits, comp);
        hipLaunchKernelGGL(k2_enc,  dim3(1280), dim3(256), 0, stream,
                           be, comp, wr, logits);
        hipLaunchKernelGGL(k2s_sm,  dim3(256),  dim3(256), 0, stream, logits);
        hipLaunchKernelGGL(k3_out,  dim3(1024), dim3(256), 0, stream,
                           x, logits, out);
    } else {
        hipLaunchKernelGGL(k_fused, dim3(256),  dim3(256), 0, stream,
                           x, Wc, bc, We, be, out);
    }
}